// Round 26
// baseline (160.324 us; speedup 1.0000x reference)
//
#include <hip/hip_runtime.h>
#include <cstddef>
#include <cstdint>

constexpr int B_ = 32;
constexpr int C_ = 512;
constexpr int N_ = 512;
constexpr int H_ = 8;
constexpr int FH_ = 1024;
constexpr float BN_EPS_ = 1e-5f;
constexpr float LOG2E_ = 1.44269504088896f;

typedef __attribute__((ext_vector_type(8))) short bf16x8;
typedef __attribute__((ext_vector_type(4))) short s16x4;
typedef __attribute__((ext_vector_type(4))) float f32x4;

enum { EPI_QKV = 0, EPI_BN1 = 1, EPI_GELU = 2, EPI_BN2 = 3 };

__device__ inline void gload_lds16(const void* g, void* l) {
    __builtin_amdgcn_global_load_lds(
        (const __attribute__((address_space(1))) void*)g,
        (__attribute__((address_space(3))) void*)l, 16, 0, 0);
}

__device__ inline short f2bf(float f) {
    union { float f; uint32_t u; } v; v.f = f;
    uint32_t r = v.u + 0x7fffu + ((v.u >> 16) & 1u);
    return (short)(r >> 16);
}

__device__ inline float bf2f(short s) {
    union { uint32_t u; float f; } v;
    v.u = ((uint32_t)(uint16_t)s) << 16;
    return v.f;
}

__device__ inline uint32_t cvt_pk_bf16(float lo, float hi) {
    uint32_t r;
    asm("v_cvt_pk_bf16_f32 %0, %1, %2" : "=v"(r) : "v"(lo), "v"(hi));
    return r;
}

// ---------------------------------------------------------------------------
// MERGED prep: blocks 0..2047 convert the four weight matrices fp32->bf16;
// blocks 2048..4095 transpose x [B][C][N] fp32 -> xT [B][N][C] bf16.
// ---------------------------------------------------------------------------
__global__ __launch_bounds__(256) void prep_fused(
    const float* __restrict__ s0, const float* __restrict__ s1,
    const float* __restrict__ s2, const float* __restrict__ s3,
    short* __restrict__ d,
    const float* __restrict__ x, short* __restrict__ xT)
{
    __shared__ __align__(16) float s[64][65];
    const int bid = blockIdx.x;
    const int t   = threadIdx.x;

    if (bid < 2048) {
        int i = bid * 256 + t;
        const float* src;
        int local;
        if (i < 196608)      { src = s0; local = i; }
        else if (i < 262144) { src = s1; local = i - 196608; }
        else if (i < 393216) { src = s2; local = i - 262144; }
        else                 { src = s3; local = i - 393216; }
        f32x4 v = *(const f32x4*)&src[(size_t)local * 4];
        s16x4 o;
        o[0] = f2bf(v[0]); o[1] = f2bf(v[1]); o[2] = f2bf(v[2]); o[3] = f2bf(v[3]);
        *(s16x4*)&d[(size_t)i * 4] = o;
        return;
    }

    const int id2 = bid - 2048;
    const int c0  = (id2 & 7) * 64;
    const int n0  = ((id2 >> 3) & 7) * 64;
    const int b   = id2 >> 6;
    const float* xb = x + ((size_t)b * C_ + c0) * N_ + n0;
    {
        int nl = t & 63, cl = t >> 6;
#pragma unroll
        for (int i = 0; i < 16; ++i)
            s[cl + i * 4][nl] = xb[(size_t)(cl + i * 4) * N_ + nl];
    }
    __syncthreads();
    short* xTb = xT + ((size_t)b * N_ + n0) * C_ + c0;
    {
        int cl = t & 63, nl = t >> 6;
#pragma unroll
        for (int i = 0; i < 16; ++i)
            xTb[(size_t)(nl + i * 4) * C_ + cl] = f2bf(s[cl][nl + i * 4]);
    }
}

// ---------------------------------------------------------------------------
// MFMA GEMM: Y[b][n][o] = sum_c A[b][n][c] * W[o][c]  (+ epilogue)
// R21/R24-proven core: 128x128 tile, BK=32, 4 waves, 3 LDS buffers,
// counted-vmcnt distance-2, T5 setprio, LDS-repack epilogues.
// ---------------------------------------------------------------------------
template <int EPI, int KD, int OSTR, int OB, int NB>
__global__ __launch_bounds__(256) void gemm_mfma(
    const short* __restrict__ A, const short* __restrict__ W,
    const float* __restrict__ bias,
    short* __restrict__ Yb, short* __restrict__ Yv, float* __restrict__ Yf,
    const short* __restrict__ resb,
    const float* __restrict__ g, const float* __restrict__ bt,
    const float* __restrict__ mn, const float* __restrict__ vr)
{
    constexpr int NWG = OB * NB * B_;
    constexpr int CPX = NWG / 8;
    const int bid = blockIdx.x;
    const int swz = (bid & 7) * CPX + (bid >> 3);
    const int ob  = swz % OB;
    const int rst = swz / OB;
    const int b   = rst / NB;
    const int o0  = ob * 128;
    const int n0  = (rst % NB) * 128;
    const short* Ab = A + (size_t)b * 512 * KD;

    __shared__ __align__(16) short smem[24576];   // 48 KB: staging + repack
    short* As = smem;                              // 3 x 4096 shorts
    short* Bs = smem + 12288;                      // 3 x 4096 shorts

    const int t = threadIdx.x;
    const int lane = t & 63, w = t >> 6;
    const int l15 = lane & 15, lg = lane >> 4;
    const int wr = w >> 1, wc = w & 1;

    const f32x4 zero4 = {0.f, 0.f, 0.f, 0.f};
    f32x4 acc[4][4];
#pragma unroll
    for (int i = 0; i < 4; ++i)
#pragma unroll
        for (int j = 0; j < 4; ++j) acc[i][j] = zero4;

    const int r0 = t >> 2;                              // staging row (0..63)
    const int kb = (((t & 3) ^ ((t >> 3) & 3)) * 8);    // swizzled source k-block

    constexpr int Kt = KD / 32;

#define GSTAGE(bufi, kk0)                                                        \
    do {                                                                         \
        gload_lds16(Ab + (size_t)(n0 + r0) * KD + (kk0) + kb,      &As[(bufi) * 4096 + w * 512]);        \
        gload_lds16(Ab + (size_t)(n0 + r0 + 64) * KD + (kk0) + kb, &As[(bufi) * 4096 + w * 512 + 2048]); \
        gload_lds16(W  + (size_t)(o0 + r0) * KD + (kk0) + kb,      &Bs[(bufi) * 4096 + w * 512]);        \
        gload_lds16(W  + (size_t)(o0 + r0 + 64) * KD + (kk0) + kb, &Bs[(bufi) * 4096 + w * 512 + 2048]); \
    } while (0)

    GSTAGE(0, 0);
    GSTAGE(1, 32);

    const int rsw = (lg ^ ((l15 >> 1) & 3)) * 8;        // swizzled read offset

#pragma unroll
    for (int k = 0; k < Kt; ++k) {                      // full unroll: k%3 static
        if (k == Kt - 1) asm volatile("s_waitcnt vmcnt(0)" ::: "memory");
        else             asm volatile("s_waitcnt vmcnt(4)" ::: "memory");
        __builtin_amdgcn_s_barrier();
        __builtin_amdgcn_sched_barrier(0);
        if (k + 2 < Kt) GSTAGE((k + 2) % 3, (k + 2) * 32);

        const int u = k % 3;
        bf16x8 af[4], bf[4];
#pragma unroll
        for (int mi = 0; mi < 4; ++mi)
            af[mi] = *(const bf16x8*)&As[u * 4096 + (wr * 64 + mi * 16 + l15) * 32 + rsw];
#pragma unroll
        for (int ni = 0; ni < 4; ++ni)
            bf[ni] = *(const bf16x8*)&Bs[u * 4096 + (wc * 64 + ni * 16 + l15) * 32 + rsw];
        __builtin_amdgcn_s_setprio(1);
#pragma unroll
        for (int mi = 0; mi < 4; ++mi)
#pragma unroll
            for (int ni = 0; ni < 4; ++ni)
                acc[mi][ni] = __builtin_amdgcn_mfma_f32_16x16x32_bf16(
                    af[mi], bf[ni], acc[mi][ni], 0, 0, 0);
        __builtin_amdgcn_s_setprio(0);
    }
#undef GSTAGE

    // ---------------- epilogue ----------------
    if constexpr (EPI == EPI_QKV) {
        if (o0 >= 1024) {
            // v-block: TRANSPOSED repack (stride 136 -> 16B-aligned reads)
            __syncthreads();
#pragma unroll
            for (int mi = 0; mi < 4; ++mi) {
                const int nb2 = wr * 64 + mi * 16 + lg * 4;     // n_local base
#pragma unroll
                for (int ni = 0; ni < 4; ++ni) {
                    const int ol = wc * 64 + ni * 16 + l15;     // o_local
                    s16x4 pk;
#pragma unroll
                    for (int r = 0; r < 4; ++r) pk[r] = f2bf(acc[mi][ni][r]);
                    *(s16x4*)&smem[ol * 136 + nb2] = pk;        // 8B ds_write
                }
            }
            __syncthreads();
            const int ov = t >> 1;                 // o_local 0..127
            const int nh = (t & 1) * 64;           // n half
            const float bvv = bias[o0 + ov];
            short* dst = Yv + ((size_t)b * 512 + (o0 - 1024) + ov) * 512 + n0 + nh;
#pragma unroll
            for (int i = 0; i < 8; ++i) {
                bf16x8 raw = *(const bf16x8*)&smem[ov * 136 + nh + i * 8];
                bf16x8 pk;
#pragma unroll
                for (int e = 0; e < 8; ++e) pk[e] = f2bf(bf2f(raw[e]) + bvv);
                *(bf16x8*)&dst[i * 8] = pk;
            }
            return;
        }
    }

    bool repack;
    if constexpr (EPI == EPI_QKV)      repack = true;   // q/k (v handled above)
    else if constexpr (EPI == EPI_BN2) repack = false;
    else                               repack = true;

    if (repack) {
        __syncthreads();          // all waves done reading staging LDS
        // write raw acc as bf16 into padded [128][132] tile
#pragma unroll
        for (int mi = 0; mi < 4; ++mi) {
            const int rowb = wr * 64 + mi * 16 + lg * 4;
#pragma unroll
            for (int ni = 0; ni < 4; ++ni) {
                const int col = wc * 64 + ni * 16 + l15;
#pragma unroll
                for (int r = 0; r < 4; ++r)
                    smem[(rowb + r) * 132 + col] = f2bf(acc[mi][ni][r]);
            }
        }
        __syncthreads();

        const int rrow = t >> 4;            // 0..15
        const int rcol = (t & 15) * 8;      // 8-short column group
        float bv8[8];
        {
            f32x4 b0 = *(const f32x4*)&bias[o0 + rcol];
            f32x4 b1 = *(const f32x4*)&bias[o0 + rcol + 4];
#pragma unroll
            for (int e = 0; e < 4; ++e) { bv8[e] = b0[e]; bv8[e + 4] = b1[e]; }
        }
        float sc8[8], sh8[8];
        if constexpr (EPI == EPI_BN1) {
            f32x4 g0 = *(const f32x4*)&g[o0 + rcol],  g1 = *(const f32x4*)&g[o0 + rcol + 4];
            f32x4 v0 = *(const f32x4*)&vr[o0 + rcol], v1 = *(const f32x4*)&vr[o0 + rcol + 4];
            f32x4 m0 = *(const f32x4*)&mn[o0 + rcol], m1 = *(const f32x4*)&mn[o0 + rcol + 4];
            f32x4 t0 = *(const f32x4*)&bt[o0 + rcol], t1 = *(const f32x4*)&bt[o0 + rcol + 4];
#pragma unroll
            for (int e = 0; e < 4; ++e) {
                sc8[e]     = g0[e] * rsqrtf(v0[e] + BN_EPS_);
                sc8[e + 4] = g1[e] * rsqrtf(v1[e] + BN_EPS_);
                sh8[e]     = t0[e] - m0[e] * sc8[e];
                sh8[e + 4] = t1[e] - m1[e] * sc8[e + 4];
            }
        }

#pragma unroll
        for (int g8 = 0; g8 < 8; ++g8) {
            const int row = g8 * 16 + rrow;
            bf16x8 raw = *(const bf16x8*)&smem[row * 132 + rcol];
            bf16x8 ov;
            if constexpr (EPI == EPI_BN1) {
                bf16x8 rr = *(const bf16x8*)&resb[((size_t)b * 512 + n0 + row) * 512 + o0 + rcol];
#pragma unroll
                for (int e = 0; e < 8; ++e) {
                    float val = (bf2f(raw[e]) + bv8[e] + bf2f(rr[e])) * sc8[e] + sh8[e];
                    ov[e] = f2bf(val);
                }
            } else if constexpr (EPI == EPI_GELU) {
#pragma unroll
                for (int e = 0; e < 8; ++e) {
                    float val = bf2f(raw[e]) + bv8[e];
                    val = 0.5f * val * (1.0f + erff(val * 0.70710678118654752f));
                    ov[e] = f2bf(val);
                }
            } else { // QKV q/k
#pragma unroll
                for (int e = 0; e < 8; ++e)
                    ov[e] = f2bf(bf2f(raw[e]) + bv8[e]);
            }
            *(bf16x8*)&Yb[((size_t)b * 512 + n0 + row) * OSTR + o0 + rcol] = ov;
        }
    } else {
        // BN2 direct (fp32 [o][n], f32x4 stores)
#pragma unroll
        for (int mi = 0; mi < 4; ++mi) {
            const int nb2 = n0 + wr * 64 + mi * 16 + lg * 4;
#pragma unroll
            for (int ni = 0; ni < 4; ++ni) {
                const int o = o0 + wc * 64 + ni * 16 + l15;
                const float bv = bias[o];
                f32x4 v = acc[mi][ni];
                const float sc = g[o] * rsqrtf(vr[o] + BN_EPS_);
                const float sh = bt[o] - mn[o] * sc;
                f32x4 ovv;
#pragma unroll
                for (int r = 0; r < 4; ++r) {
                    float hres = bf2f(resb[((size_t)b * 512 + nb2 + r) * 512 + o]);
                    ovv[r] = (v[r] + bv + hres) * sc + sh;
                }
                *(f32x4*)&Yf[((size_t)b * 512 + o) * 512 + nb2] = ovv;
            }
        }
    }
}

// ---------------------------------------------------------------------------
// Attention (flash-style, MFMA, SWAPPED QK^T). Block: (b, h, 128 q-rows),
// 512 threads / 8 waves sharing one K/V staging (R12/R21-proven schedule).
// v26: + s_setprio(1) around both MFMA clusters (T5, single-variable test
// on the proven 2-buffer schedule). Q prescaled; bias as MFMA C-in.
// Grid 1024 1-D: h = id&7 (XCD affinity), n0 = ((id>>3)&3)*128, b = id>>5.
// ---------------------------------------------------------------------------
__global__ __launch_bounds__(512) void attn_mfma(
    const short* __restrict__ qkT, const short* __restrict__ vT,
    const float* __restrict__ rel, short* __restrict__ attnT)
{
    const int id = blockIdx.x;
    const int h  = id & 7;
    const int n0 = ((id >> 3) & 3) * 128;
    const int b  = id >> 5;
    const int t  = threadIdx.x;
    const int lane = t & 63, w = t >> 6;          // w in 0..7
    const int l15 = lane & 15, lg = lane >> 4;

    __shared__ __align__(16) short Ks[2][64 * 64];
    __shared__ __align__(16) short Vs[2][64 * 64];
    __shared__ __align__(16) short Ps[8 * 16 * 64];
    __shared__ __align__(16) float relh[1024];

    const short* qb = qkT + (size_t)b * 512 * 1024;
    const short* vb = vT + (size_t)b * 512 * 512;

    for (int i = t; i < 1023; i += 512) relh[i] = rel[i * H_ + h] * LOG2E_;

    // Q direct to registers, prescaled by 0.125*log2e
    const int qr = w * 16 + l15;
    const short* qrow = qb + (size_t)(n0 + qr) * 1024 + h * 64;
    bf16x8 aq[2];
    aq[0] = *(const bf16x8*)&qrow[lg * 8];
    aq[1] = *(const bf16x8*)&qrow[32 + lg * 8];
    {
        const float scl = 0.125f * LOG2E_;
#pragma unroll
        for (int kk = 0; kk < 2; ++kk)
#pragma unroll
            for (int e = 0; e < 8; ++e)
                aq[kk][e] = f2bf(bf2f(aq[kk][e]) * scl);
    }

    // one 16B load per thread covers the whole 64x64 K (and V) tile
#define KSTAGE(bufi, m0s)                                                        \
    do {                                                                         \
        {                                                                        \
            int fl_ = t * 8;                                                     \
            int r_ = fl_ >> 6;                                                   \
            int blk_ = (fl_ >> 3) & 7;                                           \
            int d_ = ((blk_ ^ (r_ & 7)) << 3);                                   \
            gload_lds16(qb + (size_t)((m0s) + r_) * 1024 + 512 + h * 64 + d_,    \
                        &Ks[bufi][w * 512]);                                     \
        }                                                                        \
        {                                                                        \
            int fl_ = t * 8;                                                     \
            int dr_ = fl_ >> 6;                                                  \
            int blk_ = (fl_ >> 3) & 7;                                           \
            int m_ = ((blk_ ^ (dr_ & 7)) << 3);                                  \
            gload_lds16(vb + (size_t)(h * 64 + dr_) * 512 + (m0s) + m_,          \
                        &Vs[bufi][w * 512]);                                     \
        }                                                                        \
    } while (0)

    KSTAGE(0, 0);
    __syncthreads();

    const f32x4 zero4 = {0.f, 0.f, 0.f, 0.f};
    f32x4 acc_o[4];
#pragma unroll
    for (int dj = 0; dj < 4; ++dj) acc_o[dj] = zero4;

    float rmax = -3e38f, rsum = 0.f;
    const int qglob = n0 + qr;

    int cur = 0;
    for (int tile = 0; tile < 8; ++tile) {
        const int m0 = tile * 64;
        if (tile < 7) KSTAGE(cur ^ 1, m0 + 64);

        // bias preload into the accumulator (C-in): s4 starts at relh value
        const int ib = m0 + lg * 4 - qglob + 511;
        f32x4 s4[4];
#pragma unroll
        for (int mi = 0; mi < 4; ++mi)
#pragma unroll
            for (int r = 0; r < 4; ++r)
                s4[mi][r] = relh[ib + mi * 16 + r];

        // swapped QK^T (log2-domain scores accumulate onto the bias)
        __builtin_amdgcn_s_setprio(1);
#pragma unroll
        for (int kk = 0; kk < 2; ++kk) {
#pragma unroll
            for (int mi = 0; mi < 4; ++mi) {
                int mr = mi * 16 + l15;
                bf16x8 bk = *(const bf16x8*)&Ks[cur][mr * 64 + (((kk * 4 + lg) ^ (mr & 7)) << 3)];
                s4[mi] = __builtin_amdgcn_mfma_f32_16x16x32_bf16(bk, aq[kk], s4[mi], 0, 0, 0);
            }
        }
        __builtin_amdgcn_s_setprio(0);

        // in-lane max
        float tmax = -3e38f;
#pragma unroll
        for (int mi = 0; mi < 4; ++mi)
#pragma unroll
            for (int r = 0; r < 4; ++r)
                tmax = fmaxf(tmax, s4[mi][r]);
        tmax = fmaxf(tmax, __shfl_xor(tmax, 16));
        tmax = fmaxf(tmax, __shfl_xor(tmax, 32));

        // defer-max: rescale only when the new tile max exceeds rmax + 8
        if (!__all(tmax <= rmax + 8.f)) {
            float nm = fmaxf(rmax, tmax);
            float sc = __builtin_amdgcn_exp2f(rmax - nm);
            rmax = nm;
            rsum *= sc;
            float scl[4];
#pragma unroll
            for (int r = 0; r < 4; ++r)
                scl[r] = __shfl(sc, (lane & 48) | (lg * 4 + r));
#pragma unroll
            for (int dj = 0; dj < 4; ++dj)
#pragma unroll
                for (int r = 0; r < 4; ++r) acc_o[dj][r] *= scl[r];
        }

        // P = exp2(s4 - rmax), in-lane sum
        float ts = 0.f;
#pragma unroll
        for (int mi = 0; mi < 4; ++mi)
#pragma unroll
            for (int r = 0; r < 4; ++r) {
                float p = __builtin_amdgcn_exp2f(s4[mi][r] - rmax);
                s4[mi][r] = p;
                ts += p;
            }
        ts += __shfl_xor(ts, 16);
        ts += __shfl_xor(ts, 32);
        rsum += ts;

        // pack P (m-consecutive pairs) and write to LDS, XOR-swizzled.
#pragma unroll
        for (int mi = 0; mi < 4; ++mi) {
            uint32_t w01 = cvt_pk_bf16(s4[mi][0], s4[mi][1]);
            uint32_t w23 = cvt_pk_bf16(s4[mi][2], s4[mi][3]);
            int blk = mi * 2 + (lg >> 1);
            int idx = w * 1024 + l15 * 64 + ((blk ^ (l15 & 7)) << 3) + ((lg & 1) << 2);
            *(uint2*)&Ps[idx] = make_uint2(w01, w23);
        }

        // PV: A = P (rows q at l15), B = V (rows d at l15)
        __builtin_amdgcn_s_setprio(1);
#pragma unroll
        for (int kk = 0; kk < 2; ++kk) {
            bf16x8 ap = *(const bf16x8*)&Ps[w * 1024 + l15 * 64 + (((kk * 4 + lg) ^ (l15 & 7)) << 3)];
#pragma unroll
            for (int dj = 0; dj < 4; ++dj) {
                int dr = dj * 16 + l15;
                bf16x8 bv = *(const bf16x8*)&Vs[cur][dr * 64 + (((kk * 4 + lg) ^ (dr & 7)) << 3)];
                acc_o[dj] = __builtin_amdgcn_mfma_f32_16x16x32_bf16(ap, bv, acc_o[dj], 0, 0, 0);
            }
        }
        __builtin_amdgcn_s_setprio(0);
        __syncthreads();            // drains prefetch before buffer swap
        cur ^= 1;
    }
#undef KSTAGE

    // redistribute 1/rsum from q=l15 lanes to q=lg*4+reg layout
    float inv = 1.f / rsum;
    float invr[4];
#pragma unroll
    for (int r = 0; r < 4; ++r)
        invr[r] = __shfl(inv, (lane & 48) | (lg * 4 + r));

    short* ob = attnT + (size_t)b * 512 * 512;
#pragma unroll
    for (int dj = 0; dj < 4; ++dj)
#pragma unroll
        for (int reg = 0; reg < 4; ++reg) {
            int nglob = n0 + w * 16 + lg * 4 + reg;
            ob[(size_t)nglob * 512 + h * 64 + dj * 16 + l15] =
                f2bf(acc_o[dj][reg] * invr[reg]);
        }
}

// ---------------------------------------------------------------------------
extern "C" void kernel_launch(void* const* d_in, const int* in_sizes, int n_in,
                              void* d_out, int out_size, void* d_ws, size_t ws_size,
                              hipStream_t stream)
{
    const float* x      = (const float*)d_in[0];
    const float* qkv_w  = (const float*)d_in[1];
    const float* qkv_b  = (const float*)d_in[2];
    const float* out_w  = (const float*)d_in[3];
    const float* out_b  = (const float*)d_in[4];
    const float* rel    = (const float*)d_in[5];
    const float* bn1_g  = (const float*)d_in[6];
    const float* bn1_b  = (const float*)d_in[7];
    const float* bn1_m  = (const float*)d_in[8];
    const float* bn1_v  = (const float*)d_in[9];
    const float* ffn1_w = (const float*)d_in[10];
    const float* ffn1_b = (const float*)d_in[11];
    const float* ffn2_w = (const float*)d_in[12];
    const float* ffn2_b = (const float*)d_in[13];
    const float* bn2_g  = (const float*)d_in[14];
    const float* bn2_b  = (const float*)d_in[15];
    const float* bn2_m  = (const float*)d_in[16];
    const float* bn2_v  = (const float*)d_in[17];

    float* out = (float*)d_out;
    short* ws  = (short*)d_ws;

    size_t off = 0;
    short* qkvw_bf = ws + off; off += (size_t)1536 * 512;   // cvt dest is
    short* outw_bf = ws + off; off += (size_t)512 * 512;    // contiguous
    short* f1w_bf  = ws + off; off += (size_t)1024 * 512;   // across these 4
    short* f2w_bf  = ws + off; off += (size_t)512 * 1024;
    short* xT      = ws + off; off += (size_t)B_ * 512 * 512;
    short* qkT     = ws + off; off += (size_t)B_ * 512 * 1024;
    short* vTb     = ws + off; off += (size_t)B_ * 512 * 512;
    short* attnT   = ws + off; off += (size_t)B_ * 512 * 512;
    short* h_bf    = ws + off; off += (size_t)B_ * 512 * 512;
    short* f1_bf   = ws + off; off += (size_t)B_ * 512 * 1024;

    const dim3 blk(256);
    const dim3 blk512(512);

    // merged prep: weight cvt (blocks 0..2047) || x transpose (2048..4095)
    prep_fused<<<dim3(4096), blk, 0, stream>>>(qkv_w, out_w, ffn1_w, ffn2_w,
                                               qkvw_bf, x, xT);

    // 1) qkv projection (q,k -> qkT [n][1024]; v -> vTb [dv][n])
    gemm_mfma<EPI_QKV, 512, 1024, 12, 4><<<dim3(1536), blk, 0, stream>>>(
        xT, qkvw_bf, qkv_b, qkT, vTb, nullptr, nullptr, nullptr, nullptr, nullptr, nullptr);

    // 2) attention (1-D grid 1024, 512 threads, XCD-affine decode)
    attn_mfma<<<dim3(1024), blk512, 0, stream>>>(qkT, vTb, rel, attnT);

    // 3) out projection + residual(xT) + BN1 -> h_bf
    gemm_mfma<EPI_BN1, 512, 512, 4, 4><<<dim3(512), blk, 0, stream>>>(
        attnT, outw_bf, out_b, h_bf, nullptr, nullptr, xT, bn1_g, bn1_b, bn1_m, bn1_v);

    // 4) ffn1 + GELU (exact erf) -> f1_bf
    gemm_mfma<EPI_GELU, 512, 1024, 8, 4><<<dim3(1024), blk, 0, stream>>>(
        h_bf, f1w_bf, ffn1_b, f1_bf, nullptr, nullptr, nullptr, nullptr, nullptr, nullptr, nullptr);

    // 5) ffn2 + residual(h_bf) + BN2 -> out fp32 [b][c][n]
    gemm_mfma<EPI_BN2, 1024, 512, 4, 4><<<dim3(512), blk, 0, stream>>>(
        f1_bf, f2w_bf, ffn2_b, nullptr, nullptr, out, h_bf, bn2_g, bn2_b, bn2_m, bn2_v);
}

// Round 27
// 160.282 us; speedup vs baseline: 1.0003x; 1.0003x over previous
//
#include <hip/hip_runtime.h>
#include <cstddef>
#include <cstdint>

constexpr int B_ = 32;
constexpr int C_ = 512;
constexpr int N_ = 512;
constexpr int H_ = 8;
constexpr int FH_ = 1024;
constexpr float BN_EPS_ = 1e-5f;
constexpr float LOG2E_ = 1.44269504088896f;

typedef __attribute__((ext_vector_type(8))) short bf16x8;
typedef __attribute__((ext_vector_type(4))) short s16x4;
typedef __attribute__((ext_vector_type(4))) float f32x4;

enum { EPI_QKV = 0, EPI_BN1 = 1, EPI_GELU = 2, EPI_BN2 = 3 };

__device__ inline void gload_lds16(const void* g, void* l) {
    __builtin_amdgcn_global_load_lds(
        (const __attribute__((address_space(1))) void*)g,
        (__attribute__((address_space(3))) void*)l, 16, 0, 0);
}

__device__ inline short f2bf(float f) {
    union { float f; uint32_t u; } v; v.f = f;
    uint32_t r = v.u + 0x7fffu + ((v.u >> 16) & 1u);
    return (short)(r >> 16);
}

__device__ inline float bf2f(short s) {
    union { uint32_t u; float f; } v;
    v.u = ((uint32_t)(uint16_t)s) << 16;
    return v.f;
}

__device__ inline uint32_t cvt_pk_bf16(float lo, float hi) {
    uint32_t r;
    asm("v_cvt_pk_bf16_f32 %0, %1, %2" : "=v"(r) : "v"(lo), "v"(hi));
    return r;
}

// ---------------------------------------------------------------------------
// MERGED prep: blocks 0..2047 convert the four weight matrices fp32->bf16;
// blocks 2048..4095 transpose x [B][C][N] fp32 -> xT [B][N][C] bf16.
// ---------------------------------------------------------------------------
__global__ __launch_bounds__(256) void prep_fused(
    const float* __restrict__ s0, const float* __restrict__ s1,
    const float* __restrict__ s2, const float* __restrict__ s3,
    short* __restrict__ d,
    const float* __restrict__ x, short* __restrict__ xT)
{
    __shared__ __align__(16) float s[64][65];
    const int bid = blockIdx.x;
    const int t   = threadIdx.x;

    if (bid < 2048) {
        int i = bid * 256 + t;
        const float* src;
        int local;
        if (i < 196608)      { src = s0; local = i; }
        else if (i < 262144) { src = s1; local = i - 196608; }
        else if (i < 393216) { src = s2; local = i - 262144; }
        else                 { src = s3; local = i - 393216; }
        f32x4 v = *(const f32x4*)&src[(size_t)local * 4];
        s16x4 o;
        o[0] = f2bf(v[0]); o[1] = f2bf(v[1]); o[2] = f2bf(v[2]); o[3] = f2bf(v[3]);
        *(s16x4*)&d[(size_t)i * 4] = o;
        return;
    }

    const int id2 = bid - 2048;
    const int c0  = (id2 & 7) * 64;
    const int n0  = ((id2 >> 3) & 7) * 64;
    const int b   = id2 >> 6;
    const float* xb = x + ((size_t)b * C_ + c0) * N_ + n0;
    {
        int nl = t & 63, cl = t >> 6;
#pragma unroll
        for (int i = 0; i < 16; ++i)
            s[cl + i * 4][nl] = xb[(size_t)(cl + i * 4) * N_ + nl];
    }
    __syncthreads();
    short* xTb = xT + ((size_t)b * N_ + n0) * C_ + c0;
    {
        int cl = t & 63, nl = t >> 6;
#pragma unroll
        for (int i = 0; i < 16; ++i)
            xTb[(size_t)(nl + i * 4) * C_ + cl] = f2bf(s[cl][nl + i * 4]);
    }
}

// ---------------------------------------------------------------------------
// MFMA GEMM: Y[b][n][o] = sum_c A[b][n][c] * W[o][c]  (+ epilogue)
// R21/R24-proven core: 128x128 tile, BK=32, 4 waves, 3 LDS buffers,
// counted-vmcnt distance-2, T5 setprio, LDS-repack epilogues.
// ---------------------------------------------------------------------------
template <int EPI, int KD, int OSTR, int OB, int NB>
__global__ __launch_bounds__(256) void gemm_mfma(
    const short* __restrict__ A, const short* __restrict__ W,
    const float* __restrict__ bias,
    short* __restrict__ Yb, short* __restrict__ Yv, float* __restrict__ Yf,
    const short* __restrict__ resb,
    const float* __restrict__ g, const float* __restrict__ bt,
    const float* __restrict__ mn, const float* __restrict__ vr)
{
    constexpr int NWG = OB * NB * B_;
    constexpr int CPX = NWG / 8;
    const int bid = blockIdx.x;
    const int swz = (bid & 7) * CPX + (bid >> 3);
    const int ob  = swz % OB;
    const int rst = swz / OB;
    const int b   = rst / NB;
    const int o0  = ob * 128;
    const int n0  = (rst % NB) * 128;
    const short* Ab = A + (size_t)b * 512 * KD;

    __shared__ __align__(16) short smem[24576];   // 48 KB: staging + repack
    short* As = smem;                              // 3 x 4096 shorts
    short* Bs = smem + 12288;                      // 3 x 4096 shorts

    const int t = threadIdx.x;
    const int lane = t & 63, w = t >> 6;
    const int l15 = lane & 15, lg = lane >> 4;
    const int wr = w >> 1, wc = w & 1;

    const f32x4 zero4 = {0.f, 0.f, 0.f, 0.f};
    f32x4 acc[4][4];
#pragma unroll
    for (int i = 0; i < 4; ++i)
#pragma unroll
        for (int j = 0; j < 4; ++j) acc[i][j] = zero4;

    const int r0 = t >> 2;                              // staging row (0..63)
    const int kb = (((t & 3) ^ ((t >> 3) & 3)) * 8);    // swizzled source k-block

    constexpr int Kt = KD / 32;

#define GSTAGE(bufi, kk0)                                                        \
    do {                                                                         \
        gload_lds16(Ab + (size_t)(n0 + r0) * KD + (kk0) + kb,      &As[(bufi) * 4096 + w * 512]);        \
        gload_lds16(Ab + (size_t)(n0 + r0 + 64) * KD + (kk0) + kb, &As[(bufi) * 4096 + w * 512 + 2048]); \
        gload_lds16(W  + (size_t)(o0 + r0) * KD + (kk0) + kb,      &Bs[(bufi) * 4096 + w * 512]);        \
        gload_lds16(W  + (size_t)(o0 + r0 + 64) * KD + (kk0) + kb, &Bs[(bufi) * 4096 + w * 512 + 2048]); \
    } while (0)

    GSTAGE(0, 0);
    GSTAGE(1, 32);

    const int rsw = (lg ^ ((l15 >> 1) & 3)) * 8;        // swizzled read offset

#pragma unroll
    for (int k = 0; k < Kt; ++k) {                      // full unroll: k%3 static
        if (k == Kt - 1) asm volatile("s_waitcnt vmcnt(0)" ::: "memory");
        else             asm volatile("s_waitcnt vmcnt(4)" ::: "memory");
        __builtin_amdgcn_s_barrier();
        __builtin_amdgcn_sched_barrier(0);
        if (k + 2 < Kt) GSTAGE((k + 2) % 3, (k + 2) * 32);

        const int u = k % 3;
        bf16x8 af[4], bf[4];
#pragma unroll
        for (int mi = 0; mi < 4; ++mi)
            af[mi] = *(const bf16x8*)&As[u * 4096 + (wr * 64 + mi * 16 + l15) * 32 + rsw];
#pragma unroll
        for (int ni = 0; ni < 4; ++ni)
            bf[ni] = *(const bf16x8*)&Bs[u * 4096 + (wc * 64 + ni * 16 + l15) * 32 + rsw];
        __builtin_amdgcn_s_setprio(1);
#pragma unroll
        for (int mi = 0; mi < 4; ++mi)
#pragma unroll
            for (int ni = 0; ni < 4; ++ni)
                acc[mi][ni] = __builtin_amdgcn_mfma_f32_16x16x32_bf16(
                    af[mi], bf[ni], acc[mi][ni], 0, 0, 0);
        __builtin_amdgcn_s_setprio(0);
    }
#undef GSTAGE

    // ---------------- epilogue ----------------
    if constexpr (EPI == EPI_QKV) {
        if (o0 >= 1024) {
            // v-block: TRANSPOSED repack (stride 136 -> 16B-aligned reads)
            __syncthreads();
#pragma unroll
            for (int mi = 0; mi < 4; ++mi) {
                const int nb2 = wr * 64 + mi * 16 + lg * 4;     // n_local base
#pragma unroll
                for (int ni = 0; ni < 4; ++ni) {
                    const int ol = wc * 64 + ni * 16 + l15;     // o_local
                    s16x4 pk;
#pragma unroll
                    for (int r = 0; r < 4; ++r) pk[r] = f2bf(acc[mi][ni][r]);
                    *(s16x4*)&smem[ol * 136 + nb2] = pk;        // 8B ds_write
                }
            }
            __syncthreads();
            const int ov = t >> 1;                 // o_local 0..127
            const int nh = (t & 1) * 64;           // n half
            const float bvv = bias[o0 + ov];
            short* dst = Yv + ((size_t)b * 512 + (o0 - 1024) + ov) * 512 + n0 + nh;
#pragma unroll
            for (int i = 0; i < 8; ++i) {
                bf16x8 raw = *(const bf16x8*)&smem[ov * 136 + nh + i * 8];
                bf16x8 pk;
#pragma unroll
                for (int e = 0; e < 8; ++e) pk[e] = f2bf(bf2f(raw[e]) + bvv);
                *(bf16x8*)&dst[i * 8] = pk;
            }
            return;
        }
    }

    bool repack;
    if constexpr (EPI == EPI_QKV)      repack = true;   // q/k (v handled above)
    else if constexpr (EPI == EPI_BN2) repack = false;
    else                               repack = true;

    if (repack) {
        __syncthreads();          // all waves done reading staging LDS
        // write raw acc as bf16 into padded [128][132] tile
#pragma unroll
        for (int mi = 0; mi < 4; ++mi) {
            const int rowb = wr * 64 + mi * 16 + lg * 4;
#pragma unroll
            for (int ni = 0; ni < 4; ++ni) {
                const int col = wc * 64 + ni * 16 + l15;
#pragma unroll
                for (int r = 0; r < 4; ++r)
                    smem[(rowb + r) * 132 + col] = f2bf(acc[mi][ni][r]);
            }
        }
        __syncthreads();

        const int rrow = t >> 4;            // 0..15
        const int rcol = (t & 15) * 8;      // 8-short column group
        float bv8[8];
        {
            f32x4 b0 = *(const f32x4*)&bias[o0 + rcol];
            f32x4 b1 = *(const f32x4*)&bias[o0 + rcol + 4];
#pragma unroll
            for (int e = 0; e < 4; ++e) { bv8[e] = b0[e]; bv8[e + 4] = b1[e]; }
        }
        float sc8[8], sh8[8];
        if constexpr (EPI == EPI_BN1) {
            f32x4 g0 = *(const f32x4*)&g[o0 + rcol],  g1 = *(const f32x4*)&g[o0 + rcol + 4];
            f32x4 v0 = *(const f32x4*)&vr[o0 + rcol], v1 = *(const f32x4*)&vr[o0 + rcol + 4];
            f32x4 m0 = *(const f32x4*)&mn[o0 + rcol], m1 = *(const f32x4*)&mn[o0 + rcol + 4];
            f32x4 t0 = *(const f32x4*)&bt[o0 + rcol], t1 = *(const f32x4*)&bt[o0 + rcol + 4];
#pragma unroll
            for (int e = 0; e < 4; ++e) {
                sc8[e]     = g0[e] * rsqrtf(v0[e] + BN_EPS_);
                sc8[e + 4] = g1[e] * rsqrtf(v1[e] + BN_EPS_);
                sh8[e]     = t0[e] - m0[e] * sc8[e];
                sh8[e + 4] = t1[e] - m1[e] * sc8[e + 4];
            }
        }

#pragma unroll
        for (int g8 = 0; g8 < 8; ++g8) {
            const int row = g8 * 16 + rrow;
            bf16x8 raw = *(const bf16x8*)&smem[row * 132 + rcol];
            bf16x8 ov;
            if constexpr (EPI == EPI_BN1) {
                bf16x8 rr = *(const bf16x8*)&resb[((size_t)b * 512 + n0 + row) * 512 + o0 + rcol];
#pragma unroll
                for (int e = 0; e < 8; ++e) {
                    float val = (bf2f(raw[e]) + bv8[e] + bf2f(rr[e])) * sc8[e] + sh8[e];
                    ov[e] = f2bf(val);
                }
            } else if constexpr (EPI == EPI_GELU) {
#pragma unroll
                for (int e = 0; e < 8; ++e) {
                    float val = bf2f(raw[e]) + bv8[e];
                    val = 0.5f * val * (1.0f + erff(val * 0.70710678118654752f));
                    ov[e] = f2bf(val);
                }
            } else { // QKV q/k
#pragma unroll
                for (int e = 0; e < 8; ++e)
                    ov[e] = f2bf(bf2f(raw[e]) + bv8[e]);
            }
            *(bf16x8*)&Yb[((size_t)b * 512 + n0 + row) * OSTR + o0 + rcol] = ov;
        }
    } else {
        // BN2 direct (fp32 [o][n], f32x4 stores)
#pragma unroll
        for (int mi = 0; mi < 4; ++mi) {
            const int nb2 = n0 + wr * 64 + mi * 16 + lg * 4;
#pragma unroll
            for (int ni = 0; ni < 4; ++ni) {
                const int o = o0 + wc * 64 + ni * 16 + l15;
                const float bv = bias[o];
                f32x4 v = acc[mi][ni];
                const float sc = g[o] * rsqrtf(vr[o] + BN_EPS_);
                const float sh = bt[o] - mn[o] * sc;
                f32x4 ovv;
#pragma unroll
                for (int r = 0; r < 4; ++r) {
                    float hres = bf2f(resb[((size_t)b * 512 + nb2 + r) * 512 + o]);
                    ovv[r] = (v[r] + bv + hres) * sc + sh;
                }
                *(f32x4*)&Yf[((size_t)b * 512 + o) * 512 + nb2] = ovv;
            }
        }
    }
}

// ---------------------------------------------------------------------------
// Attention (flash-style, MFMA, SWAPPED QK^T). Block: (b, h, 128 q-rows),
// 512 threads / 8 waves sharing one K/V staging (R12/R21-proven schedule).
// R25-final: Q prescaled by 0.125*log2e; rel bias folded into the QK^T
// MFMA accumulator (C-in). No setprio (R26 showed neutral on this schedule).
// Grid 1024 1-D: h = id&7 (XCD affinity), n0 = ((id>>3)&3)*128, b = id>>5.
// ---------------------------------------------------------------------------
__global__ __launch_bounds__(512) void attn_mfma(
    const short* __restrict__ qkT, const short* __restrict__ vT,
    const float* __restrict__ rel, short* __restrict__ attnT)
{
    const int id = blockIdx.x;
    const int h  = id & 7;
    const int n0 = ((id >> 3) & 3) * 128;
    const int b  = id >> 5;
    const int t  = threadIdx.x;
    const int lane = t & 63, w = t >> 6;          // w in 0..7
    const int l15 = lane & 15, lg = lane >> 4;

    __shared__ __align__(16) short Ks[2][64 * 64];
    __shared__ __align__(16) short Vs[2][64 * 64];
    __shared__ __align__(16) short Ps[8 * 16 * 64];
    __shared__ __align__(16) float relh[1024];

    const short* qb = qkT + (size_t)b * 512 * 1024;
    const short* vb = vT + (size_t)b * 512 * 512;

    for (int i = t; i < 1023; i += 512) relh[i] = rel[i * H_ + h] * LOG2E_;

    // Q direct to registers, prescaled by 0.125*log2e
    const int qr = w * 16 + l15;
    const short* qrow = qb + (size_t)(n0 + qr) * 1024 + h * 64;
    bf16x8 aq[2];
    aq[0] = *(const bf16x8*)&qrow[lg * 8];
    aq[1] = *(const bf16x8*)&qrow[32 + lg * 8];
    {
        const float scl = 0.125f * LOG2E_;
#pragma unroll
        for (int kk = 0; kk < 2; ++kk)
#pragma unroll
            for (int e = 0; e < 8; ++e)
                aq[kk][e] = f2bf(bf2f(aq[kk][e]) * scl);
    }

    // one 16B load per thread covers the whole 64x64 K (and V) tile
#define KSTAGE(bufi, m0s)                                                        \
    do {                                                                         \
        {                                                                        \
            int fl_ = t * 8;                                                     \
            int r_ = fl_ >> 6;                                                   \
            int blk_ = (fl_ >> 3) & 7;                                           \
            int d_ = ((blk_ ^ (r_ & 7)) << 3);                                   \
            gload_lds16(qb + (size_t)((m0s) + r_) * 1024 + 512 + h * 64 + d_,    \
                        &Ks[bufi][w * 512]);                                     \
        }                                                                        \
        {                                                                        \
            int fl_ = t * 8;                                                     \
            int dr_ = fl_ >> 6;                                                  \
            int blk_ = (fl_ >> 3) & 7;                                           \
            int m_ = ((blk_ ^ (dr_ & 7)) << 3);                                  \
            gload_lds16(vb + (size_t)(h * 64 + dr_) * 512 + (m0s) + m_,          \
                        &Vs[bufi][w * 512]);                                     \
        }                                                                        \
    } while (0)

    KSTAGE(0, 0);
    __syncthreads();

    const f32x4 zero4 = {0.f, 0.f, 0.f, 0.f};
    f32x4 acc_o[4];
#pragma unroll
    for (int dj = 0; dj < 4; ++dj) acc_o[dj] = zero4;

    float rmax = -3e38f, rsum = 0.f;
    const int qglob = n0 + qr;

    int cur = 0;
    for (int tile = 0; tile < 8; ++tile) {
        const int m0 = tile * 64;
        if (tile < 7) KSTAGE(cur ^ 1, m0 + 64);

        // bias preload into the accumulator (C-in): s4 starts at relh value
        const int ib = m0 + lg * 4 - qglob + 511;
        f32x4 s4[4];
#pragma unroll
        for (int mi = 0; mi < 4; ++mi)
#pragma unroll
            for (int r = 0; r < 4; ++r)
                s4[mi][r] = relh[ib + mi * 16 + r];

        // swapped QK^T (log2-domain scores accumulate onto the bias)
#pragma unroll
        for (int kk = 0; kk < 2; ++kk) {
#pragma unroll
            for (int mi = 0; mi < 4; ++mi) {
                int mr = mi * 16 + l15;
                bf16x8 bk = *(const bf16x8*)&Ks[cur][mr * 64 + (((kk * 4 + lg) ^ (mr & 7)) << 3)];
                s4[mi] = __builtin_amdgcn_mfma_f32_16x16x32_bf16(bk, aq[kk], s4[mi], 0, 0, 0);
            }
        }

        // in-lane max
        float tmax = -3e38f;
#pragma unroll
        for (int mi = 0; mi < 4; ++mi)
#pragma unroll
            for (int r = 0; r < 4; ++r)
                tmax = fmaxf(tmax, s4[mi][r]);
        tmax = fmaxf(tmax, __shfl_xor(tmax, 16));
        tmax = fmaxf(tmax, __shfl_xor(tmax, 32));

        // defer-max: rescale only when the new tile max exceeds rmax + 8
        if (!__all(tmax <= rmax + 8.f)) {
            float nm = fmaxf(rmax, tmax);
            float sc = __builtin_amdgcn_exp2f(rmax - nm);
            rmax = nm;
            rsum *= sc;
            float scl[4];
#pragma unroll
            for (int r = 0; r < 4; ++r)
                scl[r] = __shfl(sc, (lane & 48) | (lg * 4 + r));
#pragma unroll
            for (int dj = 0; dj < 4; ++dj)
#pragma unroll
                for (int r = 0; r < 4; ++r) acc_o[dj][r] *= scl[r];
        }

        // P = exp2(s4 - rmax), in-lane sum
        float ts = 0.f;
#pragma unroll
        for (int mi = 0; mi < 4; ++mi)
#pragma unroll
            for (int r = 0; r < 4; ++r) {
                float p = __builtin_amdgcn_exp2f(s4[mi][r] - rmax);
                s4[mi][r] = p;
                ts += p;
            }
        ts += __shfl_xor(ts, 16);
        ts += __shfl_xor(ts, 32);
        rsum += ts;

        // pack P (m-consecutive pairs) and write to LDS, XOR-swizzled.
#pragma unroll
        for (int mi = 0; mi < 4; ++mi) {
            uint32_t w01 = cvt_pk_bf16(s4[mi][0], s4[mi][1]);
            uint32_t w23 = cvt_pk_bf16(s4[mi][2], s4[mi][3]);
            int blk = mi * 2 + (lg >> 1);
            int idx = w * 1024 + l15 * 64 + ((blk ^ (l15 & 7)) << 3) + ((lg & 1) << 2);
            *(uint2*)&Ps[idx] = make_uint2(w01, w23);
        }

        // PV: A = P (rows q at l15), B = V (rows d at l15)
#pragma unroll
        for (int kk = 0; kk < 2; ++kk) {
            bf16x8 ap = *(const bf16x8*)&Ps[w * 1024 + l15 * 64 + (((kk * 4 + lg) ^ (l15 & 7)) << 3)];
#pragma unroll
            for (int dj = 0; dj < 4; ++dj) {
                int dr = dj * 16 + l15;
                bf16x8 bv = *(const bf16x8*)&Vs[cur][dr * 64 + (((kk * 4 + lg) ^ (dr & 7)) << 3)];
                acc_o[dj] = __builtin_amdgcn_mfma_f32_16x16x32_bf16(ap, bv, acc_o[dj], 0, 0, 0);
            }
        }
        __syncthreads();            // drains prefetch before buffer swap
        cur ^= 1;
    }
#undef KSTAGE

    // redistribute 1/rsum from q=l15 lanes to q=lg*4+reg layout
    float inv = 1.f / rsum;
    float invr[4];
#pragma unroll
    for (int r = 0; r < 4; ++r)
        invr[r] = __shfl(inv, (lane & 48) | (lg * 4 + r));

    short* ob = attnT + (size_t)b * 512 * 512;
#pragma unroll
    for (int dj = 0; dj < 4; ++dj)
#pragma unroll
        for (int reg = 0; reg < 4; ++reg) {
            int nglob = n0 + w * 16 + lg * 4 + reg;
            ob[(size_t)nglob * 512 + h * 64 + dj * 16 + l15] =
                f2bf(acc_o[dj][reg] * invr[reg]);
        }
}

// ---------------------------------------------------------------------------
extern "C" void kernel_launch(void* const* d_in, const int* in_sizes, int n_in,
                              void* d_out, int out_size, void* d_ws, size_t ws_size,
                              hipStream_t stream)
{
    const float* x      = (const float*)d_in[0];
    const float* qkv_w  = (const float*)d_in[1];
    const float* qkv_b  = (const float*)d_in[2];
    const float* out_w  = (const float*)d_in[3];
    const float* out_b  = (const float*)d_in[4];
    const float* rel    = (const float*)d_in[5];
    const float* bn1_g  = (const float*)d_in[6];
    const float* bn1_b  = (const float*)d_in[7];
    const float* bn1_m  = (const float*)d_in[8];
    const float* bn1_v  = (const float*)d_in[9];
    const float* ffn1_w = (const float*)d_in[10];
    const float* ffn1_b = (const float*)d_in[11];
    const float* ffn2_w = (const float*)d_in[12];
    const float* ffn2_b = (const float*)d_in[13];
    const float* bn2_g  = (const float*)d_in[14];
    const float* bn2_b  = (const float*)d_in[15];
    const float* bn2_m  = (const float*)d_in[16];
    const float* bn2_v  = (const float*)d_in[17];

    float* out = (float*)d_out;
    short* ws  = (short*)d_ws;

    size_t off = 0;
    short* qkvw_bf = ws + off; off += (size_t)1536 * 512;   // cvt dest is
    short* outw_bf = ws + off; off += (size_t)512 * 512;    // contiguous
    short* f1w_bf  = ws + off; off += (size_t)1024 * 512;   // across these 4
    short* f2w_bf  = ws + off; off += (size_t)512 * 1024;
    short* xT      = ws + off; off += (size_t)B_ * 512 * 512;
    short* qkT     = ws + off; off += (size_t)B_ * 512 * 1024;
    short* vTb     = ws + off; off += (size_t)B_ * 512 * 512;
    short* attnT   = ws + off; off += (size_t)B_ * 512 * 512;
    short* h_bf    = ws + off; off += (size_t)B_ * 512 * 512;
    short* f1_bf   = ws + off; off += (size_t)B_ * 512 * 1024;

    const dim3 blk(256);
    const dim3 blk512(512);

    // merged prep: weight cvt (blocks 0..2047) || x transpose (2048..4095)
    prep_fused<<<dim3(4096), blk, 0, stream>>>(qkv_w, out_w, ffn1_w, ffn2_w,
                                               qkvw_bf, x, xT);

    // 1) qkv projection (q,k -> qkT [n][1024]; v -> vTb [dv][n])
    gemm_mfma<EPI_QKV, 512, 1024, 12, 4><<<dim3(1536), blk, 0, stream>>>(
        xT, qkvw_bf, qkv_b, qkT, vTb, nullptr, nullptr, nullptr, nullptr, nullptr, nullptr);

    // 2) attention (1-D grid 1024, 512 threads, XCD-affine decode)
    attn_mfma<<<dim3(1024), blk512, 0, stream>>>(qkT, vTb, rel, attnT);

    // 3) out projection + residual(xT) + BN1 -> h_bf
    gemm_mfma<EPI_BN1, 512, 512, 4, 4><<<dim3(512), blk, 0, stream>>>(
        attnT, outw_bf, out_b, h_bf, nullptr, nullptr, xT, bn1_g, bn1_b, bn1_m, bn1_v);

    // 4) ffn1 + GELU (exact erf) -> f1_bf
    gemm_mfma<EPI_GELU, 512, 1024, 8, 4><<<dim3(1024), blk, 0, stream>>>(
        h_bf, f1w_bf, ffn1_b, f1_bf, nullptr, nullptr, nullptr, nullptr, nullptr, nullptr, nullptr);

    // 5) ffn2 + residual(h_bf) + BN2 -> out fp32 [b][c][n]
    gemm_mfma<EPI_BN2, 1024, 512, 4, 4><<<dim3(512), blk, 0, stream>>>(
        f1_bf, f2w_bf, ffn2_b, nullptr, nullptr, out, h_bf, bn2_g, bn2_b, bn2_m, bn2_v);
}

// Round 28
// 160.177 us; speedup vs baseline: 1.0009x; 1.0007x over previous
//
#include <hip/hip_runtime.h>
#include <cstddef>
#include <cstdint>

constexpr int B_ = 32;
constexpr int C_ = 512;
constexpr int N_ = 512;
constexpr int H_ = 8;
constexpr int FH_ = 1024;
constexpr float BN_EPS_ = 1e-5f;
constexpr float LOG2E_ = 1.44269504088896f;

typedef __attribute__((ext_vector_type(8))) short bf16x8;
typedef __attribute__((ext_vector_type(4))) short s16x4;
typedef __attribute__((ext_vector_type(4))) float f32x4;

enum { EPI_QKV = 0, EPI_BN1 = 1, EPI_GELU = 2, EPI_BN2 = 3 };

__device__ inline void gload_lds16(const void* g, void* l) {
    __builtin_amdgcn_global_load_lds(
        (const __attribute__((address_space(1))) void*)g,
        (__attribute__((address_space(3))) void*)l, 16, 0, 0);
}

__device__ inline short f2bf(float f) {
    union { float f; uint32_t u; } v; v.f = f;
    uint32_t r = v.u + 0x7fffu + ((v.u >> 16) & 1u);
    return (short)(r >> 16);
}

__device__ inline float bf2f(short s) {
    union { uint32_t u; float f; } v;
    v.u = ((uint32_t)(uint16_t)s) << 16;
    return v.f;
}

__device__ inline uint32_t cvt_pk_bf16(float lo, float hi) {
    uint32_t r;
    asm("v_cvt_pk_bf16_f32 %0, %1, %2" : "=v"(r) : "v"(lo), "v"(hi));
    return r;
}

// ---------------------------------------------------------------------------
// MERGED prep: blocks 0..2047 convert the four weight matrices fp32->bf16;
// blocks 2048..4095 transpose x [B][C][N] fp32 -> xT [B][N][C] bf16.
// ---------------------------------------------------------------------------
__global__ __launch_bounds__(256) void prep_fused(
    const float* __restrict__ s0, const float* __restrict__ s1,
    const float* __restrict__ s2, const float* __restrict__ s3,
    short* __restrict__ d,
    const float* __restrict__ x, short* __restrict__ xT)
{
    __shared__ __align__(16) float s[64][65];
    const int bid = blockIdx.x;
    const int t   = threadIdx.x;

    if (bid < 2048) {
        int i = bid * 256 + t;
        const float* src;
        int local;
        if (i < 196608)      { src = s0; local = i; }
        else if (i < 262144) { src = s1; local = i - 196608; }
        else if (i < 393216) { src = s2; local = i - 262144; }
        else                 { src = s3; local = i - 393216; }
        f32x4 v = *(const f32x4*)&src[(size_t)local * 4];
        s16x4 o;
        o[0] = f2bf(v[0]); o[1] = f2bf(v[1]); o[2] = f2bf(v[2]); o[3] = f2bf(v[3]);
        *(s16x4*)&d[(size_t)i * 4] = o;
        return;
    }

    const int id2 = bid - 2048;
    const int c0  = (id2 & 7) * 64;
    const int n0  = ((id2 >> 3) & 7) * 64;
    const int b   = id2 >> 6;
    const float* xb = x + ((size_t)b * C_ + c0) * N_ + n0;
    {
        int nl = t & 63, cl = t >> 6;
#pragma unroll
        for (int i = 0; i < 16; ++i)
            s[cl + i * 4][nl] = xb[(size_t)(cl + i * 4) * N_ + nl];
    }
    __syncthreads();
    short* xTb = xT + ((size_t)b * N_ + n0) * C_ + c0;
    {
        int cl = t & 63, nl = t >> 6;
#pragma unroll
        for (int i = 0; i < 16; ++i)
            xTb[(size_t)(nl + i * 4) * C_ + cl] = f2bf(s[cl][nl + i * 4]);
    }
}

// ---------------------------------------------------------------------------
// MFMA GEMM: Y[b][n][o] = sum_c A[b][n][c] * W[o][c]  (+ epilogue)
// R21/R24-proven core: 128x128 tile, BK=32, 4 waves, 3 LDS buffers,
// counted-vmcnt distance-2, T5 setprio, LDS-repack epilogues.
// ---------------------------------------------------------------------------
template <int EPI, int KD, int OSTR, int OB, int NB>
__global__ __launch_bounds__(256) void gemm_mfma(
    const short* __restrict__ A, const short* __restrict__ W,
    const float* __restrict__ bias,
    short* __restrict__ Yb, short* __restrict__ Yv, float* __restrict__ Yf,
    const short* __restrict__ resb,
    const float* __restrict__ g, const float* __restrict__ bt,
    const float* __restrict__ mn, const float* __restrict__ vr)
{
    constexpr int NWG = OB * NB * B_;
    constexpr int CPX = NWG / 8;
    const int bid = blockIdx.x;
    const int swz = (bid & 7) * CPX + (bid >> 3);
    const int ob  = swz % OB;
    const int rst = swz / OB;
    const int b   = rst / NB;
    const int o0  = ob * 128;
    const int n0  = (rst % NB) * 128;
    const short* Ab = A + (size_t)b * 512 * KD;

    __shared__ __align__(16) short smem[24576];   // 48 KB: staging + repack
    short* As = smem;                              // 3 x 4096 shorts
    short* Bs = smem + 12288;                      // 3 x 4096 shorts

    const int t = threadIdx.x;
    const int lane = t & 63, w = t >> 6;
    const int l15 = lane & 15, lg = lane >> 4;
    const int wr = w >> 1, wc = w & 1;

    const f32x4 zero4 = {0.f, 0.f, 0.f, 0.f};
    f32x4 acc[4][4];
#pragma unroll
    for (int i = 0; i < 4; ++i)
#pragma unroll
        for (int j = 0; j < 4; ++j) acc[i][j] = zero4;

    const int r0 = t >> 2;                              // staging row (0..63)
    const int kb = (((t & 3) ^ ((t >> 3) & 3)) * 8);    // swizzled source k-block

    constexpr int Kt = KD / 32;

#define GSTAGE(bufi, kk0)                                                        \
    do {                                                                         \
        gload_lds16(Ab + (size_t)(n0 + r0) * KD + (kk0) + kb,      &As[(bufi) * 4096 + w * 512]);        \
        gload_lds16(Ab + (size_t)(n0 + r0 + 64) * KD + (kk0) + kb, &As[(bufi) * 4096 + w * 512 + 2048]); \
        gload_lds16(W  + (size_t)(o0 + r0) * KD + (kk0) + kb,      &Bs[(bufi) * 4096 + w * 512]);        \
        gload_lds16(W  + (size_t)(o0 + r0 + 64) * KD + (kk0) + kb, &Bs[(bufi) * 4096 + w * 512 + 2048]); \
    } while (0)

    GSTAGE(0, 0);
    GSTAGE(1, 32);

    const int rsw = (lg ^ ((l15 >> 1) & 3)) * 8;        // swizzled read offset

#pragma unroll
    for (int k = 0; k < Kt; ++k) {                      // full unroll: k%3 static
        if (k == Kt - 1) asm volatile("s_waitcnt vmcnt(0)" ::: "memory");
        else             asm volatile("s_waitcnt vmcnt(4)" ::: "memory");
        __builtin_amdgcn_s_barrier();
        __builtin_amdgcn_sched_barrier(0);
        if (k + 2 < Kt) GSTAGE((k + 2) % 3, (k + 2) * 32);

        const int u = k % 3;
        bf16x8 af[4], bf[4];
#pragma unroll
        for (int mi = 0; mi < 4; ++mi)
            af[mi] = *(const bf16x8*)&As[u * 4096 + (wr * 64 + mi * 16 + l15) * 32 + rsw];
#pragma unroll
        for (int ni = 0; ni < 4; ++ni)
            bf[ni] = *(const bf16x8*)&Bs[u * 4096 + (wc * 64 + ni * 16 + l15) * 32 + rsw];
        __builtin_amdgcn_s_setprio(1);
#pragma unroll
        for (int mi = 0; mi < 4; ++mi)
#pragma unroll
            for (int ni = 0; ni < 4; ++ni)
                acc[mi][ni] = __builtin_amdgcn_mfma_f32_16x16x32_bf16(
                    af[mi], bf[ni], acc[mi][ni], 0, 0, 0);
        __builtin_amdgcn_s_setprio(0);
    }
#undef GSTAGE

    // ---------------- epilogue ----------------
    if constexpr (EPI == EPI_QKV) {
        if (o0 >= 1024) {
            // v-block: TRANSPOSED repack (stride 136 -> 16B-aligned reads)
            __syncthreads();
#pragma unroll
            for (int mi = 0; mi < 4; ++mi) {
                const int nb2 = wr * 64 + mi * 16 + lg * 4;     // n_local base
#pragma unroll
                for (int ni = 0; ni < 4; ++ni) {
                    const int ol = wc * 64 + ni * 16 + l15;     // o_local
                    s16x4 pk;
#pragma unroll
                    for (int r = 0; r < 4; ++r) pk[r] = f2bf(acc[mi][ni][r]);
                    *(s16x4*)&smem[ol * 136 + nb2] = pk;        // 8B ds_write
                }
            }
            __syncthreads();
            const int ov = t >> 1;                 // o_local 0..127
            const int nh = (t & 1) * 64;           // n half
            const float bvv = bias[o0 + ov];
            short* dst = Yv + ((size_t)b * 512 + (o0 - 1024) + ov) * 512 + n0 + nh;
#pragma unroll
            for (int i = 0; i < 8; ++i) {
                bf16x8 raw = *(const bf16x8*)&smem[ov * 136 + nh + i * 8];
                bf16x8 pk;
#pragma unroll
                for (int e = 0; e < 8; ++e) pk[e] = f2bf(bf2f(raw[e]) + bvv);
                *(bf16x8*)&dst[i * 8] = pk;
            }
            return;
        }
    }

    bool repack;
    if constexpr (EPI == EPI_QKV)      repack = true;   // q/k (v handled above)
    else if constexpr (EPI == EPI_BN2) repack = false;
    else                               repack = true;

    if (repack) {
        __syncthreads();          // all waves done reading staging LDS
        // write raw acc as bf16 into padded [128][132] tile
#pragma unroll
        for (int mi = 0; mi < 4; ++mi) {
            const int rowb = wr * 64 + mi * 16 + lg * 4;
#pragma unroll
            for (int ni = 0; ni < 4; ++ni) {
                const int col = wc * 64 + ni * 16 + l15;
#pragma unroll
                for (int r = 0; r < 4; ++r)
                    smem[(rowb + r) * 132 + col] = f2bf(acc[mi][ni][r]);
            }
        }
        __syncthreads();

        const int rrow = t >> 4;            // 0..15
        const int rcol = (t & 15) * 8;      // 8-short column group
        float bv8[8];
        {
            f32x4 b0 = *(const f32x4*)&bias[o0 + rcol];
            f32x4 b1 = *(const f32x4*)&bias[o0 + rcol + 4];
#pragma unroll
            for (int e = 0; e < 4; ++e) { bv8[e] = b0[e]; bv8[e + 4] = b1[e]; }
        }
        float sc8[8], sh8[8];
        if constexpr (EPI == EPI_BN1) {
            f32x4 g0 = *(const f32x4*)&g[o0 + rcol],  g1 = *(const f32x4*)&g[o0 + rcol + 4];
            f32x4 v0 = *(const f32x4*)&vr[o0 + rcol], v1 = *(const f32x4*)&vr[o0 + rcol + 4];
            f32x4 m0 = *(const f32x4*)&mn[o0 + rcol], m1 = *(const f32x4*)&mn[o0 + rcol + 4];
            f32x4 t0 = *(const f32x4*)&bt[o0 + rcol], t1 = *(const f32x4*)&bt[o0 + rcol + 4];
#pragma unroll
            for (int e = 0; e < 4; ++e) {
                sc8[e]     = g0[e] * rsqrtf(v0[e] + BN_EPS_);
                sc8[e + 4] = g1[e] * rsqrtf(v1[e] + BN_EPS_);
                sh8[e]     = t0[e] - m0[e] * sc8[e];
                sh8[e + 4] = t1[e] - m1[e] * sc8[e + 4];
            }
        }

#pragma unroll
        for (int g8 = 0; g8 < 8; ++g8) {
            const int row = g8 * 16 + rrow;
            bf16x8 raw = *(const bf16x8*)&smem[row * 132 + rcol];
            bf16x8 ov;
            if constexpr (EPI == EPI_BN1) {
                bf16x8 rr = *(const bf16x8*)&resb[((size_t)b * 512 + n0 + row) * 512 + o0 + rcol];
#pragma unroll
                for (int e = 0; e < 8; ++e) {
                    float val = (bf2f(raw[e]) + bv8[e] + bf2f(rr[e])) * sc8[e] + sh8[e];
                    ov[e] = f2bf(val);
                }
            } else if constexpr (EPI == EPI_GELU) {
#pragma unroll
                for (int e = 0; e < 8; ++e) {
                    float val = bf2f(raw[e]) + bv8[e];
                    val = 0.5f * val * (1.0f + erff(val * 0.70710678118654752f));
                    ov[e] = f2bf(val);
                }
            } else { // QKV q/k
#pragma unroll
                for (int e = 0; e < 8; ++e)
                    ov[e] = f2bf(bf2f(raw[e]) + bv8[e]);
            }
            *(bf16x8*)&Yb[((size_t)b * 512 + n0 + row) * OSTR + o0 + rcol] = ov;
        }
    } else {
        // BN2 direct (fp32 [o][n], f32x4 stores)
#pragma unroll
        for (int mi = 0; mi < 4; ++mi) {
            const int nb2 = n0 + wr * 64 + mi * 16 + lg * 4;
#pragma unroll
            for (int ni = 0; ni < 4; ++ni) {
                const int o = o0 + wc * 64 + ni * 16 + l15;
                const float bv = bias[o];
                f32x4 v = acc[mi][ni];
                const float sc = g[o] * rsqrtf(vr[o] + BN_EPS_);
                const float sh = bt[o] - mn[o] * sc;
                f32x4 ovv;
#pragma unroll
                for (int r = 0; r < 4; ++r) {
                    float hres = bf2f(resb[((size_t)b * 512 + nb2 + r) * 512 + o]);
                    ovv[r] = (v[r] + bv + hres) * sc + sh;
                }
                *(f32x4*)&Yf[((size_t)b * 512 + o) * 512 + nb2] = ovv;
            }
        }
    }
}

// ---------------------------------------------------------------------------
// Attention (flash-style, MFMA, SWAPPED QK^T). Block: (b, h, 128 q-rows),
// 512 threads / 8 waves sharing one K/V staging (R12/R21-proven schedule).
// R25-final: Q prescaled by 0.125*log2e; rel bias folded into the QK^T
// MFMA accumulator (C-in). No setprio (R26 showed neutral on this schedule).
// Grid 1024 1-D: h = id&7 (XCD affinity), n0 = ((id>>3)&3)*128, b = id>>5.
// ---------------------------------------------------------------------------
__global__ __launch_bounds__(512) void attn_mfma(
    const short* __restrict__ qkT, const short* __restrict__ vT,
    const float* __restrict__ rel, short* __restrict__ attnT)
{
    const int id = blockIdx.x;
    const int h  = id & 7;
    const int n0 = ((id >> 3) & 3) * 128;
    const int b  = id >> 5;
    const int t  = threadIdx.x;
    const int lane = t & 63, w = t >> 6;          // w in 0..7
    const int l15 = lane & 15, lg = lane >> 4;

    __shared__ __align__(16) short Ks[2][64 * 64];
    __shared__ __align__(16) short Vs[2][64 * 64];
    __shared__ __align__(16) short Ps[8 * 16 * 64];
    __shared__ __align__(16) float relh[1024];

    const short* qb = qkT + (size_t)b * 512 * 1024;
    const short* vb = vT + (size_t)b * 512 * 512;

    for (int i = t; i < 1023; i += 512) relh[i] = rel[i * H_ + h] * LOG2E_;

    // Q direct to registers, prescaled by 0.125*log2e
    const int qr = w * 16 + l15;
    const short* qrow = qb + (size_t)(n0 + qr) * 1024 + h * 64;
    bf16x8 aq[2];
    aq[0] = *(const bf16x8*)&qrow[lg * 8];
    aq[1] = *(const bf16x8*)&qrow[32 + lg * 8];
    {
        const float scl = 0.125f * LOG2E_;
#pragma unroll
        for (int kk = 0; kk < 2; ++kk)
#pragma unroll
            for (int e = 0; e < 8; ++e)
                aq[kk][e] = f2bf(bf2f(aq[kk][e]) * scl);
    }

    // one 16B load per thread covers the whole 64x64 K (and V) tile
#define KSTAGE(bufi, m0s)                                                        \
    do {                                                                         \
        {                                                                        \
            int fl_ = t * 8;                                                     \
            int r_ = fl_ >> 6;                                                   \
            int blk_ = (fl_ >> 3) & 7;                                           \
            int d_ = ((blk_ ^ (r_ & 7)) << 3);                                   \
            gload_lds16(qb + (size_t)((m0s) + r_) * 1024 + 512 + h * 64 + d_,    \
                        &Ks[bufi][w * 512]);                                     \
        }                                                                        \
        {                                                                        \
            int fl_ = t * 8;                                                     \
            int dr_ = fl_ >> 6;                                                  \
            int blk_ = (fl_ >> 3) & 7;                                           \
            int m_ = ((blk_ ^ (dr_ & 7)) << 3);                                  \
            gload_lds16(vb + (size_t)(h * 64 + dr_) * 512 + (m0s) + m_,          \
                        &Vs[bufi][w * 512]);                                     \
        }                                                                        \
    } while (0)

    KSTAGE(0, 0);
    __syncthreads();

    const f32x4 zero4 = {0.f, 0.f, 0.f, 0.f};
    f32x4 acc_o[4];
#pragma unroll
    for (int dj = 0; dj < 4; ++dj) acc_o[dj] = zero4;

    float rmax = -3e38f, rsum = 0.f;
    const int qglob = n0 + qr;

    int cur = 0;
    for (int tile = 0; tile < 8; ++tile) {
        const int m0 = tile * 64;
        if (tile < 7) KSTAGE(cur ^ 1, m0 + 64);

        // bias preload into the accumulator (C-in): s4 starts at relh value
        const int ib = m0 + lg * 4 - qglob + 511;
        f32x4 s4[4];
#pragma unroll
        for (int mi = 0; mi < 4; ++mi)
#pragma unroll
            for (int r = 0; r < 4; ++r)
                s4[mi][r] = relh[ib + mi * 16 + r];

        // swapped QK^T (log2-domain scores accumulate onto the bias)
#pragma unroll
        for (int kk = 0; kk < 2; ++kk) {
#pragma unroll
            for (int mi = 0; mi < 4; ++mi) {
                int mr = mi * 16 + l15;
                bf16x8 bk = *(const bf16x8*)&Ks[cur][mr * 64 + (((kk * 4 + lg) ^ (mr & 7)) << 3)];
                s4[mi] = __builtin_amdgcn_mfma_f32_16x16x32_bf16(bk, aq[kk], s4[mi], 0, 0, 0);
            }
        }

        // in-lane max
        float tmax = -3e38f;
#pragma unroll
        for (int mi = 0; mi < 4; ++mi)
#pragma unroll
            for (int r = 0; r < 4; ++r)
                tmax = fmaxf(tmax, s4[mi][r]);
        tmax = fmaxf(tmax, __shfl_xor(tmax, 16));
        tmax = fmaxf(tmax, __shfl_xor(tmax, 32));

        // defer-max: rescale only when the new tile max exceeds rmax + 8
        if (!__all(tmax <= rmax + 8.f)) {
            float nm = fmaxf(rmax, tmax);
            float sc = __builtin_amdgcn_exp2f(rmax - nm);
            rmax = nm;
            rsum *= sc;
            float scl[4];
#pragma unroll
            for (int r = 0; r < 4; ++r)
                scl[r] = __shfl(sc, (lane & 48) | (lg * 4 + r));
#pragma unroll
            for (int dj = 0; dj < 4; ++dj)
#pragma unroll
                for (int r = 0; r < 4; ++r) acc_o[dj][r] *= scl[r];
        }

        // P = exp2(s4 - rmax), in-lane sum
        float ts = 0.f;
#pragma unroll
        for (int mi = 0; mi < 4; ++mi)
#pragma unroll
            for (int r = 0; r < 4; ++r) {
                float p = __builtin_amdgcn_exp2f(s4[mi][r] - rmax);
                s4[mi][r] = p;
                ts += p;
            }
        ts += __shfl_xor(ts, 16);
        ts += __shfl_xor(ts, 32);
        rsum += ts;

        // pack P (m-consecutive pairs) and write to LDS, XOR-swizzled.
#pragma unroll
        for (int mi = 0; mi < 4; ++mi) {
            uint32_t w01 = cvt_pk_bf16(s4[mi][0], s4[mi][1]);
            uint32_t w23 = cvt_pk_bf16(s4[mi][2], s4[mi][3]);
            int blk = mi * 2 + (lg >> 1);
            int idx = w * 1024 + l15 * 64 + ((blk ^ (l15 & 7)) << 3) + ((lg & 1) << 2);
            *(uint2*)&Ps[idx] = make_uint2(w01, w23);
        }

        // PV: A = P (rows q at l15), B = V (rows d at l15)
#pragma unroll
        for (int kk = 0; kk < 2; ++kk) {
            bf16x8 ap = *(const bf16x8*)&Ps[w * 1024 + l15 * 64 + (((kk * 4 + lg) ^ (l15 & 7)) << 3)];
#pragma unroll
            for (int dj = 0; dj < 4; ++dj) {
                int dr = dj * 16 + l15;
                bf16x8 bv = *(const bf16x8*)&Vs[cur][dr * 64 + (((kk * 4 + lg) ^ (dr & 7)) << 3)];
                acc_o[dj] = __builtin_amdgcn_mfma_f32_16x16x32_bf16(ap, bv, acc_o[dj], 0, 0, 0);
            }
        }
        __syncthreads();            // drains prefetch before buffer swap
        cur ^= 1;
    }
#undef KSTAGE

    // redistribute 1/rsum from q=l15 lanes to q=lg*4+reg layout
    float inv = 1.f / rsum;
    float invr[4];
#pragma unroll
    for (int r = 0; r < 4; ++r)
        invr[r] = __shfl(inv, (lane & 48) | (lg * 4 + r));

    short* ob = attnT + (size_t)b * 512 * 512;
#pragma unroll
    for (int dj = 0; dj < 4; ++dj)
#pragma unroll
        for (int reg = 0; reg < 4; ++reg) {
            int nglob = n0 + w * 16 + lg * 4 + reg;
            ob[(size_t)nglob * 512 + h * 64 + dj * 16 + l15] =
                f2bf(acc_o[dj][reg] * invr[reg]);
        }
}

// ---------------------------------------------------------------------------
extern "C" void kernel_launch(void* const* d_in, const int* in_sizes, int n_in,
                              void* d_out, int out_size, void* d_ws, size_t ws_size,
                              hipStream_t stream)
{
    const float* x      = (const float*)d_in[0];
    const float* qkv_w  = (const float*)d_in[1];
    const float* qkv_b  = (const float*)d_in[2];
    const float* out_w  = (const float*)d_in[3];
    const float* out_b  = (const float*)d_in[4];
    const float* rel    = (const float*)d_in[5];
    const float* bn1_g  = (const float*)d_in[6];
    const float* bn1_b  = (const float*)d_in[7];
    const float* bn1_m  = (const float*)d_in[8];
    const float* bn1_v  = (const float*)d_in[9];
    const float* ffn1_w = (const float*)d_in[10];
    const float* ffn1_b = (const float*)d_in[11];
    const float* ffn2_w = (const float*)d_in[12];
    const float* ffn2_b = (const float*)d_in[13];
    const float* bn2_g  = (const float*)d_in[14];
    const float* bn2_b  = (const float*)d_in[15];
    const float* bn2_m  = (const float*)d_in[16];
    const float* bn2_v  = (const float*)d_in[17];

    float* out = (float*)d_out;
    short* ws  = (short*)d_ws;

    size_t off = 0;
    short* qkvw_bf = ws + off; off += (size_t)1536 * 512;   // cvt dest is
    short* outw_bf = ws + off; off += (size_t)512 * 512;    // contiguous
    short* f1w_bf  = ws + off; off += (size_t)1024 * 512;   // across these 4
    short* f2w_bf  = ws + off; off += (size_t)512 * 1024;
    short* xT      = ws + off; off += (size_t)B_ * 512 * 512;
    short* qkT     = ws + off; off += (size_t)B_ * 512 * 1024;
    short* vTb     = ws + off; off += (size_t)B_ * 512 * 512;
    short* attnT   = ws + off; off += (size_t)B_ * 512 * 512;
    short* h_bf    = ws + off; off += (size_t)B_ * 512 * 512;
    short* f1_bf   = ws + off; off += (size_t)B_ * 512 * 1024;

    const dim3 blk(256);
    const dim3 blk512(512);

    // merged prep: weight cvt (blocks 0..2047) || x transpose (2048..4095)
    prep_fused<<<dim3(4096), blk, 0, stream>>>(qkv_w, out_w, ffn1_w, ffn2_w,
                                               qkvw_bf, x, xT);

    // 1) qkv projection (q,k -> qkT [n][1024]; v -> vTb [dv][n])
    gemm_mfma<EPI_QKV, 512, 1024, 12, 4><<<dim3(1536), blk, 0, stream>>>(
        xT, qkvw_bf, qkv_b, qkT, vTb, nullptr, nullptr, nullptr, nullptr, nullptr, nullptr);

    // 2) attention (1-D grid 1024, 512 threads, XCD-affine decode)
    attn_mfma<<<dim3(1024), blk512, 0, stream>>>(qkT, vTb, rel, attnT);

    // 3) out projection + residual(xT) + BN1 -> h_bf
    gemm_mfma<EPI_BN1, 512, 512, 4, 4><<<dim3(512), blk, 0, stream>>>(
        attnT, outw_bf, out_b, h_bf, nullptr, nullptr, xT, bn1_g, bn1_b, bn1_m, bn1_v);

    // 4) ffn1 + GELU (exact erf) -> f1_bf
    gemm_mfma<EPI_GELU, 512, 1024, 8, 4><<<dim3(1024), blk, 0, stream>>>(
        h_bf, f1w_bf, ffn1_b, f1_bf, nullptr, nullptr, nullptr, nullptr, nullptr, nullptr, nullptr);

    // 5) ffn2 + residual(h_bf) + BN2 -> out fp32 [b][c][n]
    gemm_mfma<EPI_BN2, 1024, 512, 4, 4><<<dim3(512), blk, 0, stream>>>(
        f1_bf, f2w_bf, ffn2_b, nullptr, nullptr, out, h_bf, bn2_g, bn2_b, bn2_m, bn2_v);
}